// Round 1
// baseline (819.203 us; speedup 1.0000x reference)
//
#include <hip/hip_runtime.h>

typedef unsigned int u32;
typedef unsigned short u16;
typedef unsigned long long u64;
typedef _Float16 f16;
typedef _Float16 f16x2 __attribute__((ext_vector_type(2)));

#define Bn 256
#define Sn 200
#define Dn 128
#define Mn 64
#define NQn 5000

__device__ __forceinline__ float fdot2f(u32 w, u32 x, float acc) {
#if __has_builtin(__builtin_amdgcn_fdot2)
    return __builtin_amdgcn_fdot2(__builtin_bit_cast(f16x2, w),
                                  __builtin_bit_cast(f16x2, x), acc, false);
#else
    f16x2 a = __builtin_bit_cast(f16x2, w);
    f16x2 b = __builtin_bit_cast(f16x2, x);
    return acc + (float)a[0] * (float)b[0] + (float)a[1] * (float)b[1];
#endif
}

__device__ __forceinline__ u32 packh2(float a, float b) {
    u16 ua = __builtin_bit_cast(u16, (f16)a);
    u16 ub = __builtin_bit_cast(u16, (f16)b);
    return (u32)ua | ((u32)ub << 16);
}

__device__ __forceinline__ float sigf(float x) { return 1.0f / (1.0f + expf(-x)); }

// ---------------------------------------------------------------------------
// Kernel A: per (b,s): cw = softmax(k @ Mk^T)  (fp32, binning-critical),
// store cw as f16, and the iv-code as two 64-bit ballots.
// One wave per item, 8 items (waves) per block.
// ---------------------------------------------------------------------------
__global__ __launch_bounds__(512) void phase0_kernel(
    const int* __restrict__ qseq,
    const float* __restrict__ Mk, const float* __restrict__ embc,
    u16* __restrict__ cw16, ulonglong2* __restrict__ codes)
{
    __shared__ float MkT[Dn * 65];      // transposed, padded: bank-conflict-free
    __shared__ float kb[8][Dn];
    int tid = threadIdx.x;
    for (int idx = tid; idx < Mn * Dn; idx += 512) {
        int m = idx >> 7, d = idx & 127;
        MkT[d * 65 + m] = Mk[idx];
    }
    __syncthreads();
    int w = tid >> 6, lane = tid & 63;
    int item = blockIdx.x * 8 + w;      // item = b*Sn + s
    int qq = qseq[item];
    kb[w][lane]      = embc[qq * Dn + lane];
    kb[w][lane + 64] = embc[qq * Dn + lane + 64];
    __syncthreads();
    float acc = 0.0f;
    const float* kw = kb[w];
#pragma unroll 8
    for (int d = 0; d < Dn; ++d)
        acc = fmaf(MkT[d * 65 + lane], kw[d], acc);
    // softmax over 64 lanes (m dimension)
    float mx = acc;
    for (int off = 32; off; off >>= 1) mx = fmaxf(mx, __shfl_xor(mx, off));
    float e = expf(acc - mx);
    float sm = e;
    for (int off = 32; off; off >>= 1) sm += __shfl_xor(sm, off);
    float cw = e / sm;
    cw16[item * Mn + lane] = __builtin_bit_cast(u16, (f16)cw);
    // triangular membership -> identity value (bit-match the np formulas)
    float t1 = (cw - 0.01f) / (0.05f - 0.01f);
    float t2 = (0.1f - cw) / (0.1f - 0.05f);
    float tri = fminf(t1, t2);
    tri = fmaxf(tri, 0.0f);
    int iv = (tri >= 0.6f) ? 2 : ((tri >= 0.1f) ? 1 : 0);
    u64 b1 = __ballot(iv >= 1);
    u64 b2 = __ballot(iv == 2);
    if (lane == 0) { codes[item].x = b1; codes[item].y = b2; }
}

// ---------------------------------------------------------------------------
// Kernel B: prev_t[b,t] = max{ j < t : code[j]==code[t] } else -1.
// One block per b.
// ---------------------------------------------------------------------------
__global__ __launch_bounds__(256) void match_kernel(
    const ulonglong2* __restrict__ codes, int* __restrict__ prev)
{
    __shared__ u64 clo[Sn], chi[Sn];
    int b = blockIdx.x, tid = threadIdx.x;
    if (tid < Sn) { ulonglong2 c = codes[b * Sn + tid]; clo[tid] = c.x; chi[tid] = c.y; }
    __syncthreads();
    if (tid < Sn) {
        u64 mylo = clo[tid], myhi = chi[tid];
        int best = -1;
        for (int j = 0; j < tid; ++j)
            if (clo[j] == mylo && chi[j] == myhi) best = j;
        prev[b * Sn + tid] = best;
    }
}

// ---------------------------------------------------------------------------
// Kernel C: DKVMN value-memory recurrence. One block (512 thr) per b.
// mem[64][128] in registers (16/thread), weights f16x2 in registers (96/thread),
// activations fp32/f16 in LDS. Emits ft (f16) for the LSTM.
// thread -> (d = tid>>2, q = tid&3); owns m in [q*16, q*16+16) and col chunk q*32..+32.
// ---------------------------------------------------------------------------
__global__ __launch_bounds__(512, 2) void memrec_kernel(
    const int* __restrict__ qseq, const int* __restrict__ cseq,
    const float* __restrict__ Mv0,
    const float* __restrict__ embc, const float* __restrict__ embi,
    const float* __restrict__ Wf, const float* __restrict__ bfv,
    const float* __restrict__ Wa, const float* __restrict__ bav,
    const float* __restrict__ We, const float* __restrict__ bev,
    const float* __restrict__ Wadd, const float* __restrict__ badv,
    const u16* __restrict__ cw16, u16* __restrict__ ft16)
{
    __shared__ __align__(16) u32 kbuf[64], ybuf[64], rbuf[64], fbuf[64], wbuf[64]; // 128 f16 each
    __shared__ __align__(16) float cwbuf[2][64];
    __shared__ float ebuf[Dn], abuf[Dn];
    __shared__ float bfL[Dn], baL[Dn], beL[Dn], badL[Dn];
    __shared__ int qnx, cnx;

    int tid = threadIdx.x;
    int d = tid >> 2, q = tid & 3;
    int b = blockIdx.x;

    u32 wfk[16], wfr[16], way[16], waf[16], wew[16], wadw[16];
    {
        const float2* wf2r = (const float2*)(Wf + d * 256 + q * 32);
        const float2* wf2k = (const float2*)(Wf + d * 256 + 128 + q * 32);
        const float2* wa2f = (const float2*)(Wa + d * 256 + q * 32);
        const float2* wa2y = (const float2*)(Wa + d * 256 + 128 + q * 32);
        const float2* we2  = (const float2*)(We + d * 128 + q * 32);
        const float2* wd2  = (const float2*)(Wadd + d * 128 + q * 32);
#pragma unroll
        for (int i = 0; i < 16; ++i) {
            float2 a;
            a = wf2r[i]; wfr[i]  = packh2(a.x, a.y);
            a = wf2k[i]; wfk[i]  = packh2(a.x, a.y);
            a = wa2f[i]; waf[i]  = packh2(a.x, a.y);
            a = wa2y[i]; way[i]  = packh2(a.x, a.y);
            a = we2[i];  wew[i]  = packh2(a.x, a.y);
            a = wd2[i];  wadw[i] = packh2(a.x, a.y);
        }
    }
    float memv[16];
#pragma unroll
    for (int i = 0; i < 16; ++i) memv[i] = Mv0[(q * 16 + i) * Dn + d];

    if (tid < Dn) { bfL[tid] = bfv[tid]; baL[tid] = bav[tid]; beL[tid] = bev[tid]; badL[tid] = badv[tid]; }

    // preamble loads for t=0
    {
        int q0 = qseq[b * Sn], c0 = cseq[b * Sn];
        if (tid < 128)      ((f16*)kbuf)[tid] = (f16)embc[q0 * Dn + tid];
        else if (tid < 256) ((f16*)ybuf)[tid - 128] = (f16)embi[(q0 + NQn * c0) * Dn + (tid - 128)];
        else if (tid < 320) {
            u16 u = cw16[(b * Sn) * Mn + (tid - 256)];
            cwbuf[0][tid - 256] = (float)__builtin_bit_cast(f16, u);
        }
    }
    __syncthreads();

    for (int t = 0; t < Sn; ++t) {
        int cur = t & 1;
        // ---- P1: k-half of f, y-half of we, read partial -------------------
        float accf = 0.0f, accw = 0.0f, pr = 0.0f;
#pragma unroll
        for (int u = 0; u < 4; ++u) {
            uint4 x = ((const uint4*)kbuf)[(q << 2) + u];
            accf = fdot2f(wfk[4 * u + 0], x.x, accf);
            accf = fdot2f(wfk[4 * u + 1], x.y, accf);
            accf = fdot2f(wfk[4 * u + 2], x.z, accf);
            accf = fdot2f(wfk[4 * u + 3], x.w, accf);
        }
#pragma unroll
        for (int u = 0; u < 4; ++u) {
            uint4 x = ((const uint4*)ybuf)[(q << 2) + u];
            accw = fdot2f(way[4 * u + 0], x.x, accw);
            accw = fdot2f(way[4 * u + 1], x.y, accw);
            accw = fdot2f(way[4 * u + 2], x.z, accw);
            accw = fdot2f(way[4 * u + 3], x.w, accw);
        }
#pragma unroll
        for (int u = 0; u < 4; ++u) {
            float4 c4 = ((const float4*)(cwbuf[cur]))[(q << 2) + u];
            pr = fmaf(c4.x, memv[4 * u + 0], pr);
            pr = fmaf(c4.y, memv[4 * u + 1], pr);
            pr = fmaf(c4.z, memv[4 * u + 2], pr);
            pr = fmaf(c4.w, memv[4 * u + 3], pr);
        }
        pr += __shfl_xor(pr, 1);
        pr += __shfl_xor(pr, 2);
        if (q == 0) ((f16*)rbuf)[d] = (f16)pr;
        if (t + 1 < Sn && tid == 508) { qnx = qseq[b * Sn + t + 1]; cnx = cseq[b * Sn + t + 1]; }
        __syncthreads();
        // ---- P2: f = tanh(Wf[:, :128] @ read + khalf + bf) -----------------
#pragma unroll
        for (int u = 0; u < 4; ++u) {
            uint4 x = ((const uint4*)rbuf)[(q << 2) + u];
            accf = fdot2f(wfr[4 * u + 0], x.x, accf);
            accf = fdot2f(wfr[4 * u + 1], x.y, accf);
            accf = fdot2f(wfr[4 * u + 2], x.z, accf);
            accf = fdot2f(wfr[4 * u + 3], x.w, accf);
        }
        accf += __shfl_xor(accf, 1);
        accf += __shfl_xor(accf, 2);
        if (q == 0) {
            float fv = tanhf(accf + bfL[d]);
            ((f16*)fbuf)[d] = (f16)fv;
            ft16[(b * Sn + t) * Dn + d] = __builtin_bit_cast(u16, (f16)fv);
        }
        __syncthreads();
        // ---- P3: we = Wa[:, :128] @ f + yhalf + ba -------------------------
#pragma unroll
        for (int u = 0; u < 4; ++u) {
            uint4 x = ((const uint4*)fbuf)[(q << 2) + u];
            accw = fdot2f(waf[4 * u + 0], x.x, accw);
            accw = fdot2f(waf[4 * u + 1], x.y, accw);
            accw = fdot2f(waf[4 * u + 2], x.z, accw);
            accw = fdot2f(waf[4 * u + 3], x.w, accw);
        }
        accw += __shfl_xor(accw, 1);
        accw += __shfl_xor(accw, 2);
        if (q == 0) ((f16*)wbuf)[d] = (f16)(accw + baL[d]);
        __syncthreads();
        // ---- P4: erase = sig(We@we+be), add = tanh(Wadd@we+badd) -----------
        float pe = 0.0f, pa = 0.0f;
#pragma unroll
        for (int u = 0; u < 4; ++u) {
            uint4 x = ((const uint4*)wbuf)[(q << 2) + u];
            pe = fdot2f(wew[4 * u + 0], x.x, pe);  pa = fdot2f(wadw[4 * u + 0], x.x, pa);
            pe = fdot2f(wew[4 * u + 1], x.y, pe);  pa = fdot2f(wadw[4 * u + 1], x.y, pa);
            pe = fdot2f(wew[4 * u + 2], x.z, pe);  pa = fdot2f(wadw[4 * u + 2], x.z, pa);
            pe = fdot2f(wew[4 * u + 3], x.w, pe);  pa = fdot2f(wadw[4 * u + 3], x.w, pa);
        }
        pe += __shfl_xor(pe, 1); pe += __shfl_xor(pe, 2);
        pa += __shfl_xor(pa, 1); pa += __shfl_xor(pa, 2);
        if (q == 0) ebuf[d] = sigf(pe + beL[d]);
        if (q == 1) abuf[d] = tanhf(pa + badL[d]);
        __syncthreads();
        // ---- P5: mem update + loads for t+1 --------------------------------
        {
            float e = ebuf[d], a = abuf[d];
#pragma unroll
            for (int i = 0; i < 16; ++i) {
                float c = cwbuf[cur][q * 16 + i];
                float tt = fmaf(-e, memv[i], a);      // a - e*mem
                memv[i] = fmaf(c, tt, memv[i]);       // mem + c*(a - e*mem)
            }
        }
        if (t + 1 < Sn) {
            int qq = qnx, cc = cnx;
            if (tid < 128)      ((f16*)kbuf)[tid] = (f16)embc[qq * Dn + tid];
            else if (tid < 256) ((f16*)ybuf)[tid - 128] = (f16)embi[(qq + NQn * cc) * Dn + (tid - 128)];
            else if (tid < 320) {
                u16 u = cw16[(b * Sn + t + 1) * Mn + (tid - 256)];
                cwbuf[1 - cur][tid - 256] = (float)__builtin_bit_cast(f16, u);
            }
        }
        __syncthreads();
    }
}

// ---------------------------------------------------------------------------
// Kernel D: hop-LSTM. One block (512 thr) per b. Thread g owns full rows
// W_ih[g,:], W_hh[g,:] as f16x2 in registers (128 regs). H history as f16
// pairs in LDS (rows: 0 = hx0, 1+t = h_t). cx fp32 in registers of threads<128.
// ---------------------------------------------------------------------------
__global__ __launch_bounds__(512, 2) void lstm_kernel(
    const float* __restrict__ W_ih, const float* __restrict__ W_hh,
    const float* __restrict__ b_ih, const float* __restrict__ b_hh,
    const float* __restrict__ hx0, const float* __restrict__ cx0,
    const float* __restrict__ Wp, const float* __restrict__ bp,
    const u16* __restrict__ ft16, const int* __restrict__ prev,
    float* __restrict__ out)
{
    __shared__ __align__(16) u32 HL[(Sn + 1) * 64];  // 201 rows of 128 f16
    __shared__ __align__(16) u32 fxb[2][64];
    __shared__ float gbuf[4 * Dn];
    __shared__ float bsum[4 * Dn];
    __shared__ int prevL[Sn];
    __shared__ u32 wpL[64];
    __shared__ float bpL;

    int tid = threadIdx.x, b = blockIdx.x;
    u32 wih[64], whh[64];
    {
        const float2* wi2 = (const float2*)(W_ih + tid * Dn);
        const float2* wh2 = (const float2*)(W_hh + tid * Dn);
#pragma unroll
        for (int i = 0; i < 64; ++i) {
            float2 a;
            a = wi2[i]; wih[i] = packh2(a.x, a.y);
            a = wh2[i]; whh[i] = packh2(a.x, a.y);
        }
    }
    bsum[tid] = b_ih[tid] + b_hh[tid];
    if (tid < 64) {
        HL[tid]  = packh2(hx0[2 * tid], hx0[2 * tid + 1]);
        wpL[tid] = packh2(Wp[2 * tid], Wp[2 * tid + 1]);
        fxb[0][tid] = ((const u32*)ft16)[(b * Sn) * 64 + tid];
    }
    if (tid < Sn) prevL[tid] = prev[b * Sn + tid];
    if (tid == 0) bpL = bp[0];
    float cx = (tid < Dn) ? cx0[tid] : 0.0f;
    __syncthreads();

    for (int t = 0; t < Sn; ++t) {
        int cur = t & 1;
        int pv = prevL[t];
        int hrow = (pv >= 0) ? (pv + 1) : t;   // t=0: pv=-1 -> row 0 = hx0
        const uint4* h4 = (const uint4*)(HL + hrow * 64);
        const uint4* f4 = (const uint4*)(fxb[cur]);
        float acc = bsum[tid];
#pragma unroll
        for (int u = 0; u < 16; ++u) {
            uint4 x = f4[u];
            acc = fdot2f(wih[4 * u + 0], x.x, acc);
            acc = fdot2f(wih[4 * u + 1], x.y, acc);
            acc = fdot2f(wih[4 * u + 2], x.z, acc);
            acc = fdot2f(wih[4 * u + 3], x.w, acc);
        }
#pragma unroll
        for (int u = 0; u < 16; ++u) {
            uint4 x = h4[u];
            acc = fdot2f(whh[4 * u + 0], x.x, acc);
            acc = fdot2f(whh[4 * u + 1], x.y, acc);
            acc = fdot2f(whh[4 * u + 2], x.z, acc);
            acc = fdot2f(whh[4 * u + 3], x.w, acc);
        }
        gbuf[tid] = acc;
        if (t + 1 < Sn && tid < 64)
            fxb[1 - cur][tid] = ((const u32*)ft16)[(b * Sn + t + 1) * 64 + tid];
        __syncthreads();
        if (tid < Dn) {
            float ig = sigf(gbuf[tid]);
            float fg = sigf(gbuf[Dn + tid]);
            float gg = tanhf(gbuf[2 * Dn + tid]);
            float og = sigf(gbuf[3 * Dn + tid]);
            cx = fg * cx + ig * gg;
            float h = og * tanhf(cx);
            ((f16*)HL)[(t + 1) * Dn + tid] = (f16)h;
        }
        __syncthreads();
    }
    // logits for all t from resident H
    if (tid < Sn) {
        float acc = 0.0f;
        const u32* hr = HL + (tid + 1) * 64;
#pragma unroll 16
        for (int j = 0; j < 64; ++j) acc = fdot2f(hr[j], wpL[j], acc);
        out[b * Sn + tid] = sigf(acc + bpL);
    }
}

// ---------------------------------------------------------------------------
extern "C" void kernel_launch(void* const* d_in, const int* in_sizes, int n_in,
                              void* d_out, int out_size, void* d_ws, size_t ws_size,
                              hipStream_t stream) {
    const int*   qseq = (const int*)d_in[0];
    const int*   cseq = (const int*)d_in[1];
    const float* Mk   = (const float*)d_in[2];
    const float* Mv0  = (const float*)d_in[3];
    const float* embc = (const float*)d_in[4];
    const float* embi = (const float*)d_in[5];
    const float* Wf   = (const float*)d_in[6];
    const float* bfv  = (const float*)d_in[7];
    const float* Wa   = (const float*)d_in[8];
    const float* bav  = (const float*)d_in[9];
    const float* We   = (const float*)d_in[10];
    const float* bev  = (const float*)d_in[11];
    const float* Wadd = (const float*)d_in[12];
    const float* badv = (const float*)d_in[13];
    const float* W_ih = (const float*)d_in[14];
    const float* W_hh = (const float*)d_in[15];
    const float* b_ih = (const float*)d_in[16];
    const float* b_hh = (const float*)d_in[17];
    const float* hx0  = (const float*)d_in[18];
    const float* cx0  = (const float*)d_in[19];
    const float* Wp   = (const float*)d_in[20];
    const float* bp   = (const float*)d_in[21];
    float* out = (float*)d_out;

    char* ws = (char*)d_ws;
    u16* cw16 = (u16*)ws;                                   // B*S*M*2  = 6,553,600 B
    u16* ft16 = (u16*)(ws + 6553600);                       // B*S*D*2  = 13,107,200 B
    ulonglong2* codes = (ulonglong2*)(ws + 19660800);       // B*S*16   = 819,200 B
    int* prev = (int*)(ws + 20480000);                      // B*S*4    = 204,800 B

    phase0_kernel<<<(Bn * Sn) / 8, 512, 0, stream>>>(qseq, Mk, embc, cw16, codes);
    match_kernel<<<Bn, 256, 0, stream>>>(codes, prev);
    memrec_kernel<<<Bn, 512, 0, stream>>>(qseq, cseq, Mv0, embc, embi,
                                          Wf, bfv, Wa, bav, We, bev, Wadd, badv,
                                          cw16, ft16);
    lstm_kernel<<<Bn, 512, 0, stream>>>(W_ih, W_hh, b_ih, b_hh, hx0, cx0, Wp, bp,
                                        ft16, prev, out);
}

// Round 2
// 628.815 us; speedup vs baseline: 1.3028x; 1.3028x over previous
//
#include <hip/hip_runtime.h>

typedef unsigned int u32;
typedef unsigned short u16;
typedef unsigned long long u64;
typedef _Float16 f16;
typedef _Float16 f16x2 __attribute__((ext_vector_type(2)));

#define Bn 256
#define Sn 200
#define Dn 128
#define Mn 64
#define NQn 5000

__device__ __forceinline__ float fdot2f(u32 w, u32 x, float acc) {
#if __has_builtin(__builtin_amdgcn_fdot2)
    return __builtin_amdgcn_fdot2(__builtin_bit_cast(f16x2, w),
                                  __builtin_bit_cast(f16x2, x), acc, false);
#else
    f16x2 a = __builtin_bit_cast(f16x2, w);
    f16x2 b = __builtin_bit_cast(f16x2, x);
    return acc + (float)a[0] * (float)b[0] + (float)a[1] * (float)b[1];
#endif
}

__device__ __forceinline__ u32 packh2(float a, float b) {
    u16 ua = __builtin_bit_cast(u16, (f16)a);
    u16 ub = __builtin_bit_cast(u16, (f16)b);
    return (u32)ua | ((u32)ub << 16);
}

__device__ __forceinline__ float h2f(u16 u) { return (float)__builtin_bit_cast(f16, u); }

__device__ __forceinline__ float fexp2f(float x) {
#if __has_builtin(__builtin_amdgcn_exp2f)
    return __builtin_amdgcn_exp2f(x);
#else
    return exp2f(x);
#endif
}
__device__ __forceinline__ float frcpf(float x) {
#if __has_builtin(__builtin_amdgcn_rcpf)
    return __builtin_amdgcn_rcpf(x);
#else
    return 1.0f / x;
#endif
}
// sigmoid(x) = 1/(1+2^(-x*log2e));  tanh(x) = 1 - 2/(1+2^(x*2*log2e))
__device__ __forceinline__ float sig_fast(float x)  { return frcpf(1.0f + fexp2f(-1.44269504f * x)); }
__device__ __forceinline__ float tanh_fast(float x) { return fmaf(-2.0f, frcpf(1.0f + fexp2f(2.88539008f * x)), 1.0f); }

__device__ __forceinline__ float sigf(float x) { return 1.0f / (1.0f + expf(-x)); }

// ---------------------------------------------------------------------------
// Kernel A: per (b,s): cw = softmax(k @ Mk^T)  (fp32, binning-critical),
// store cw as f16, and the iv-code as two 64-bit ballots. (unchanged, passing)
// ---------------------------------------------------------------------------
__global__ __launch_bounds__(512) void phase0_kernel(
    const int* __restrict__ qseq,
    const float* __restrict__ Mk, const float* __restrict__ embc,
    u16* __restrict__ cw16, ulonglong2* __restrict__ codes)
{
    __shared__ float MkT[Dn * 65];
    __shared__ float kb[8][Dn];
    int tid = threadIdx.x;
    for (int idx = tid; idx < Mn * Dn; idx += 512) {
        int m = idx >> 7, d = idx & 127;
        MkT[d * 65 + m] = Mk[idx];
    }
    __syncthreads();
    int w = tid >> 6, lane = tid & 63;
    int item = blockIdx.x * 8 + w;
    int qq = qseq[item];
    kb[w][lane]      = embc[qq * Dn + lane];
    kb[w][lane + 64] = embc[qq * Dn + lane + 64];
    __syncthreads();
    float acc = 0.0f;
    const float* kw = kb[w];
#pragma unroll 8
    for (int d = 0; d < Dn; ++d)
        acc = fmaf(MkT[d * 65 + lane], kw[d], acc);
    float mx = acc;
    for (int off = 32; off; off >>= 1) mx = fmaxf(mx, __shfl_xor(mx, off));
    float e = expf(acc - mx);
    float sm = e;
    for (int off = 32; off; off >>= 1) sm += __shfl_xor(sm, off);
    float cw = e / sm;
    cw16[item * Mn + lane] = __builtin_bit_cast(u16, (f16)cw);
    float t1 = (cw - 0.01f) / (0.05f - 0.01f);
    float t2 = (0.1f - cw) / (0.1f - 0.05f);
    float tri = fminf(t1, t2);
    tri = fmaxf(tri, 0.0f);
    int iv = (tri >= 0.6f) ? 2 : ((tri >= 0.1f) ? 1 : 0);
    u64 b1 = __ballot(iv >= 1);
    u64 b2 = __ballot(iv == 2);
    if (lane == 0) { codes[item].x = b1; codes[item].y = b2; }
}

// ---------------------------------------------------------------------------
// Kernel B: prev_t match. (unchanged)
// ---------------------------------------------------------------------------
__global__ __launch_bounds__(256) void match_kernel(
    const ulonglong2* __restrict__ codes, int* __restrict__ prev)
{
    __shared__ u64 clo[Sn], chi[Sn];
    int b = blockIdx.x, tid = threadIdx.x;
    if (tid < Sn) { ulonglong2 c = codes[b * Sn + tid]; clo[tid] = c.x; chi[tid] = c.y; }
    __syncthreads();
    if (tid < Sn) {
        u64 mylo = clo[tid], myhi = chi[tid];
        int best = -1;
        for (int j = 0; j < tid; ++j)
            if (clo[j] == mylo && chi[j] == myhi) best = j;
        prev[b * Sn + tid] = best;
    }
}

// ---------------------------------------------------------------------------
// Kernel P: hoisted recurrence-independent matvecs.
// out[item][d] = sum_j W[d][128+j] * emb[row][j]   (f16 weights, fp32 acc)
// mode 0: row = qseq[item]; mode 1: row = qseq[item] + NQn*cseq[item].
// One wave per item, 8 items/block, weights staged f16 in LDS (padded).
// ---------------------------------------------------------------------------
__global__ __launch_bounds__(512) void pre_kernel(
    const float* __restrict__ W, const float* __restrict__ emb,
    const int* __restrict__ qseq, const int* __restrict__ cseq, int mode,
    u16* __restrict__ outp)
{
    __shared__ u32 wL[128 * 65];        // 33.3 KB, row stride 65 breaks conflicts
    __shared__ u32 vb[8][64];
    int tid = threadIdx.x;
    for (int idx = tid; idx < 128 * 64; idx += 512) {
        int dd = idx >> 6, jj = idx & 63;
        const float2 wv = *(const float2*)(W + dd * 256 + 128 + 2 * jj);
        wL[dd * 65 + jj] = packh2(wv.x, wv.y);
    }
    int w = tid >> 6, lane = tid & 63;
    int item = blockIdx.x * 8 + w;
    int row = qseq[item];
    if (mode) row += NQn * cseq[item];
    {
        const float2 kv = *(const float2*)(emb + row * Dn + 2 * lane);
        vb[w][lane] = packh2(kv.x, kv.y);
    }
    __syncthreads();
    const u32* w0 = wL + lane * 65;
    const u32* w1 = wL + (64 + lane) * 65;
    const u32* x  = vb[w];
    float a0 = 0, a1 = 0, b0 = 0, b1 = 0;
#pragma unroll
    for (int jj = 0; jj < 64; jj += 2) {
        a0 = fdot2f(w0[jj],     x[jj],     a0);
        a1 = fdot2f(w0[jj + 1], x[jj + 1], a1);
        b0 = fdot2f(w1[jj],     x[jj],     b0);
        b1 = fdot2f(w1[jj + 1], x[jj + 1], b1);
    }
    outp[item * Dn + lane]      = __builtin_bit_cast(u16, (f16)(a0 + a1));
    outp[item * Dn + 64 + lane] = __builtin_bit_cast(u16, (f16)(b0 + b1));
}

// ---------------------------------------------------------------------------
// Kernel C: DKVMN value-memory recurrence. One block (512 thr) per b.
// 3 barriers/step; NO global loads inside barrier phases except the ft16
// store (ack overlapped) and once-per-16-step chunk staging of kf/ya.
// cw for all 200 steps preloaded in LDS. thread -> (d = tid>>2, q = tid&3).
// ---------------------------------------------------------------------------
__global__ __launch_bounds__(512, 2) void memrec_kernel(
    const float* __restrict__ Mv0,
    const float* __restrict__ Wf, const float* __restrict__ bfv,
    const float* __restrict__ Wa, const float* __restrict__ bav,
    const float* __restrict__ We, const float* __restrict__ bev,
    const float* __restrict__ Wadd, const float* __restrict__ badv,
    const u16* __restrict__ cw16, const u16* __restrict__ kf16,
    const u16* __restrict__ ya16, u16* __restrict__ ft16)
{
    __shared__ u32 cwL[Sn * 32];                    // 25.6 KB: all-t cw (f16 pairs)
    __shared__ __align__(16) u32 kfb[2][16 * 64];   // 8 KB: 16-step kf chunk, dbuf
    __shared__ __align__(16) u32 yab[2][16 * 64];   // 8 KB
    __shared__ __align__(16) u32 rbuf[64], fbuf[64], wbuf[64];
    __shared__ float bfL[Dn], baL[Dn], beL[Dn], badL[Dn];

    int tid = threadIdx.x;
    int d = tid >> 2, q = tid & 3;
    int b = blockIdx.x;

    u32 wfr[16], waf[16], wew[16], wadw[16];
    {
        const float2* wf2r = (const float2*)(Wf + d * 256 + q * 32);
        const float2* wa2f = (const float2*)(Wa + d * 256 + q * 32);
        const float2* we2  = (const float2*)(We + d * 128 + q * 32);
        const float2* wd2  = (const float2*)(Wadd + d * 128 + q * 32);
#pragma unroll
        for (int i = 0; i < 16; ++i) {
            float2 a;
            a = wf2r[i]; wfr[i]  = packh2(a.x, a.y);
            a = wa2f[i]; waf[i]  = packh2(a.x, a.y);
            a = we2[i];  wew[i]  = packh2(a.x, a.y);
            a = wd2[i];  wadw[i] = packh2(a.x, a.y);
        }
    }
    float memv[16];
#pragma unroll
    for (int i = 0; i < 16; ++i) memv[i] = Mv0[(q * 16 + i) * Dn + d];

    if (tid < Dn) { bfL[tid] = bfv[tid]; baL[tid] = bav[tid]; beL[tid] = bev[tid]; badL[tid] = badv[tid]; }

    // preload all cw; stage chunk 0 of kf/ya
    for (int i = tid; i < Sn * 32; i += 512) cwL[i] = ((const u32*)cw16)[b * Sn * 32 + i];
    {
        const u32* kg = (const u32*)kf16 + (size_t)(b * Sn) * 64;
        const u32* yg = (const u32*)ya16 + (size_t)(b * Sn) * 64;
        for (int i = tid; i < 1024; i += 512) { kfb[0][i] = kg[i]; yab[0][i] = yg[i]; }
    }
    __syncthreads();

    float cwreg[16];
#pragma unroll
    for (int i = 0; i < 8; ++i) {
        u32 v = cwL[q * 8 + i];
        cwreg[2 * i]     = h2f((u16)(v & 0xffff));
        cwreg[2 * i + 1] = h2f((u16)(v >> 16));
    }

    for (int t = 0; t < Sn; ++t) {
        int sl = (t >> 4) & 1, ti = t & 15;
        if (ti == 0) {                       // stage next 16-step kf/ya chunk
            int c1 = (t >> 4) + 1;
            if (c1 * 16 < Sn) {
                int n = (Sn - c1 * 16 < 16 ? Sn - c1 * 16 : 16) * 64;
                const u32* kg = (const u32*)kf16 + (size_t)(b * Sn + c1 * 16) * 64;
                const u32* yg = (const u32*)ya16 + (size_t)(b * Sn + c1 * 16) * 64;
                for (int i = tid; i < n; i += 512) { kfb[sl ^ 1][i] = kg[i]; yab[sl ^ 1][i] = yg[i]; }
            }
        }
        // ---- P1: read partial -------------------------------------------
        float p0 = 0, p1 = 0, p2 = 0, p3 = 0;
#pragma unroll
        for (int i = 0; i < 4; ++i) {
            p0 = fmaf(cwreg[i],      memv[i],      p0);
            p1 = fmaf(cwreg[4 + i],  memv[4 + i],  p1);
            p2 = fmaf(cwreg[8 + i],  memv[8 + i],  p2);
            p3 = fmaf(cwreg[12 + i], memv[12 + i], p3);
        }
        float pr = (p0 + p1) + (p2 + p3);
        pr += __shfl_xor(pr, 1);
        pr += __shfl_xor(pr, 2);
        if (q == 0) ((f16*)rbuf)[d] = (f16)pr;
        __syncthreads();                                        // B1
        // ---- P2: f = tanh(Wf_r @ read + kf_t + bf) ----------------------
        u16 kfc = ((const u16*)(kfb[sl]))[ti * 128 + d];
        float a0 = 0, a1 = 0, a2 = 0, a3 = 0;
#pragma unroll
        for (int u = 0; u < 4; ++u) {
            uint4 x = ((const uint4*)rbuf)[(q << 2) + u];
            a0 = fdot2f(wfr[4 * u + 0], x.x, a0);
            a1 = fdot2f(wfr[4 * u + 1], x.y, a1);
            a2 = fdot2f(wfr[4 * u + 2], x.z, a2);
            a3 = fdot2f(wfr[4 * u + 3], x.w, a3);
        }
        float accf = (a0 + a1) + (a2 + a3);
        accf += __shfl_xor(accf, 1);
        accf += __shfl_xor(accf, 2);
        float fv = tanh_fast(accf + h2f(kfc) + bfL[d]);
        if (q == 0) ((f16*)fbuf)[d] = (f16)fv;
        if (q == 1) ft16[(size_t)(b * Sn + t) * Dn + d] = __builtin_bit_cast(u16, (f16)fv);
        __syncthreads();                                        // B2
        // ---- P3: we = Wa_f @ f + ya_t + ba ------------------------------
        u16 yac = ((const u16*)(yab[sl]))[ti * 128 + d];
        float c0 = 0, c1_ = 0, c2 = 0, c3 = 0;
#pragma unroll
        for (int u = 0; u < 4; ++u) {
            uint4 x = ((const uint4*)fbuf)[(q << 2) + u];
            c0  = fdot2f(waf[4 * u + 0], x.x, c0);
            c1_ = fdot2f(waf[4 * u + 1], x.y, c1_);
            c2  = fdot2f(waf[4 * u + 2], x.z, c2);
            c3  = fdot2f(waf[4 * u + 3], x.w, c3);
        }
        float accw = (c0 + c1_) + (c2 + c3);
        accw += __shfl_xor(accw, 1);
        accw += __shfl_xor(accw, 2);
        if (q == 0) ((f16*)wbuf)[d] = (f16)(accw + h2f(yac) + baL[d]);
        __syncthreads();                                        // B3
        // ---- P4: erase/add (quad-redundant, no barrier) + mem update ----
        float e0 = 0, e1 = 0, g0 = 0, g1 = 0;
#pragma unroll
        for (int u = 0; u < 4; ++u) {
            uint4 x = ((const uint4*)wbuf)[(q << 2) + u];
            e0 = fdot2f(wew[4 * u + 0], x.x, e0);   g0 = fdot2f(wadw[4 * u + 0], x.x, g0);
            e1 = fdot2f(wew[4 * u + 1], x.y, e1);   g1 = fdot2f(wadw[4 * u + 1], x.y, g1);
            e0 = fdot2f(wew[4 * u + 2], x.z, e0);   g0 = fdot2f(wadw[4 * u + 2], x.z, g0);
            e1 = fdot2f(wew[4 * u + 3], x.w, e1);   g1 = fdot2f(wadw[4 * u + 3], x.w, g1);
        }
        float pe = e0 + e1, pa = g0 + g1;
        pe += __shfl_xor(pe, 1); pe += __shfl_xor(pe, 2);
        pa += __shfl_xor(pa, 1); pa += __shfl_xor(pa, 2);
        float ev = sig_fast(pe + beL[d]);
        float av = tanh_fast(pa + badL[d]);
        u32 cwn[8];
        if (t + 1 < Sn) {
#pragma unroll
            for (int i = 0; i < 8; ++i) cwn[i] = cwL[(t + 1) * 32 + q * 8 + i];
        }
#pragma unroll
        for (int i = 0; i < 16; ++i) {
            float tt = fmaf(-ev, memv[i], av);      // add - erase*mem
            memv[i] = fmaf(cwreg[i], tt, memv[i]);
        }
        if (t + 1 < Sn) {
#pragma unroll
            for (int i = 0; i < 8; ++i) {
                cwreg[2 * i]     = h2f((u16)(cwn[i] & 0xffff));
                cwreg[2 * i + 1] = h2f((u16)(cwn[i] >> 16));
            }
        }
    }
}

// ---------------------------------------------------------------------------
// Kernel D: hop-LSTM. One block (512 thr) per b. ft chunk-staged 16 steps
// at a time (no per-step global loads in barrier phases); fast activations.
// ---------------------------------------------------------------------------
__global__ __launch_bounds__(512, 2) void lstm_kernel(
    const float* __restrict__ W_ih, const float* __restrict__ W_hh,
    const float* __restrict__ b_ih, const float* __restrict__ b_hh,
    const float* __restrict__ hx0, const float* __restrict__ cx0,
    const float* __restrict__ Wp, const float* __restrict__ bp,
    const u16* __restrict__ ft16, const int* __restrict__ prev,
    float* __restrict__ out)
{
    __shared__ u32 HL[(Sn + 1) * 64];               // 51.4 KB: h history f16
    __shared__ __align__(16) u32 ftb[2][16 * 64];   // 8 KB: 16-step ft chunk
    __shared__ float gbuf[512];
    __shared__ float bsum[512];
    __shared__ int prevL[Sn];
    __shared__ u32 wpL[64];
    __shared__ float bpL;

    int tid = threadIdx.x, b = blockIdx.x;
    u32 wih[64], whh[64];
    {
        const float2* wi2 = (const float2*)(W_ih + tid * Dn);
        const float2* wh2 = (const float2*)(W_hh + tid * Dn);
#pragma unroll
        for (int i = 0; i < 64; ++i) {
            float2 a;
            a = wi2[i]; wih[i] = packh2(a.x, a.y);
            a = wh2[i]; whh[i] = packh2(a.x, a.y);
        }
    }
    bsum[tid] = b_ih[tid] + b_hh[tid];
    if (tid < 64) {
        HL[tid]  = packh2(hx0[2 * tid], hx0[2 * tid + 1]);
        wpL[tid] = packh2(Wp[2 * tid], Wp[2 * tid + 1]);
    }
    if (tid < Sn) prevL[tid] = prev[b * Sn + tid];
    if (tid == 0) bpL = bp[0];
    float cx = (tid < Dn) ? cx0[tid] : 0.0f;
    {
        const u32* fg = (const u32*)ft16 + (size_t)(b * Sn) * 64;
        for (int i = tid; i < 1024; i += 512) ftb[0][i] = fg[i];
    }
    __syncthreads();

    for (int t = 0; t < Sn; ++t) {
        int sl = (t >> 4) & 1, ti = t & 15;
        if (ti == 0) {
            int c1 = (t >> 4) + 1;
            if (c1 * 16 < Sn) {
                int n = (Sn - c1 * 16 < 16 ? Sn - c1 * 16 : 16) * 64;
                const u32* fg = (const u32*)ft16 + (size_t)(b * Sn + c1 * 16) * 64;
                for (int i = tid; i < n; i += 512) ftb[sl ^ 1][i] = fg[i];
            }
        }
        int pv = prevL[t];
        int hrow = (pv >= 0) ? (pv + 1) : t;
        const uint4* h4 = (const uint4*)(HL + hrow * 64);
        const uint4* f4 = (const uint4*)(ftb[sl] + ti * 64);
        float a0 = bsum[tid], a1 = 0, a2 = 0, a3 = 0;
        float b0 = 0, b1 = 0, b2 = 0, b3 = 0;
#pragma unroll
        for (int u = 0; u < 4; ++u) {
            uint4 x = f4[u];
            a0 = fdot2f(wih[4 * u + 0], x.x, a0);
            a1 = fdot2f(wih[4 * u + 1], x.y, a1);
            a2 = fdot2f(wih[4 * u + 2], x.z, a2);
            a3 = fdot2f(wih[4 * u + 3], x.w, a3);
            uint4 y = h4[u];
            b0 = fdot2f(whh[4 * u + 0], y.x, b0);
            b1 = fdot2f(whh[4 * u + 1], y.y, b1);
            b2 = fdot2f(whh[4 * u + 2], y.z, b2);
            b3 = fdot2f(whh[4 * u + 3], y.w, b3);
        }
        gbuf[tid] = ((a0 + a1) + (a2 + a3)) + ((b0 + b1) + (b2 + b3));
        __syncthreads();
        if (tid < 128) {
            float ig = sig_fast(gbuf[tid]);
            float fg = sig_fast(gbuf[128 + tid]);
            float gg = tanh_fast(gbuf[256 + tid]);
            float og = sig_fast(gbuf[384 + tid]);
            cx = fmaf(fg, cx, ig * gg);
            float h = og * tanh_fast(cx);
            ((f16*)HL)[(t + 1) * Dn + tid] = (f16)h;
        }
        __syncthreads();
    }
    if (tid < Sn) {
        float acc = 0.0f;
        const u32* hr = HL + (tid + 1) * 64;
#pragma unroll 16
        for (int j = 0; j < 64; ++j) acc = fdot2f(hr[j], wpL[j], acc);
        out[b * Sn + tid] = sig_fast(acc + bpL);
    }
}

// ---------------------------------------------------------------------------
extern "C" void kernel_launch(void* const* d_in, const int* in_sizes, int n_in,
                              void* d_out, int out_size, void* d_ws, size_t ws_size,
                              hipStream_t stream) {
    const int*   qseq = (const int*)d_in[0];
    const int*   cseq = (const int*)d_in[1];
    const float* Mk   = (const float*)d_in[2];
    const float* Mv0  = (const float*)d_in[3];
    const float* embc = (const float*)d_in[4];
    const float* embi = (const float*)d_in[5];
    const float* Wf   = (const float*)d_in[6];
    const float* bfv  = (const float*)d_in[7];
    const float* Wa   = (const float*)d_in[8];
    const float* bav  = (const float*)d_in[9];
    const float* We   = (const float*)d_in[10];
    const float* bev  = (const float*)d_in[11];
    const float* Wadd = (const float*)d_in[12];
    const float* badv = (const float*)d_in[13];
    const float* W_ih = (const float*)d_in[14];
    const float* W_hh = (const float*)d_in[15];
    const float* b_ih = (const float*)d_in[16];
    const float* b_hh = (const float*)d_in[17];
    const float* hx0  = (const float*)d_in[18];
    const float* cx0  = (const float*)d_in[19];
    const float* Wp   = (const float*)d_in[20];
    const float* bp   = (const float*)d_in[21];
    float* out = (float*)d_out;

    char* ws = (char*)d_ws;
    u16* cw16 = (u16*)ws;                              // 6,553,600 B
    u16* ft16 = (u16*)(ws + 6553600);                  // 13,107,200 B
    ulonglong2* codes = (ulonglong2*)(ws + 19660800);  // 819,200 B
    int* prev = (int*)(ws + 20480000);                 // 204,800 B
    u16* kf16 = (u16*)(ws + 20684800);                 // 13,107,200 B
    u16* ya16 = (u16*)(ws + 33792000);                 // 13,107,200 B -> ends 46.9 MB

    phase0_kernel<<<(Bn * Sn) / 8, 512, 0, stream>>>(qseq, Mk, embc, cw16, codes);
    pre_kernel<<<(Bn * Sn) / 8, 512, 0, stream>>>(Wf, embc, qseq, cseq, 0, kf16);
    pre_kernel<<<(Bn * Sn) / 8, 512, 0, stream>>>(Wa, embi, qseq, cseq, 1, ya16);
    match_kernel<<<Bn, 256, 0, stream>>>(codes, prev);
    memrec_kernel<<<Bn, 512, 0, stream>>>(Mv0, Wf, bfv, Wa, bav, We, bev, Wadd, badv,
                                          cw16, kf16, ya16, ft16);
    lstm_kernel<<<Bn, 512, 0, stream>>>(W_ih, W_hh, b_ih, b_hh, hx0, cx0, Wp, bp,
                                        ft16, prev, out);
}